// Round 4
// baseline (68.375 us; speedup 1.0000x reference)
//
#include <hip/hip_runtime.h>
#include <math.h>

#define BATCH 8192
#define NTASK 1024
#define NF 256
#define NH 64

// d_ws layout (ints): [0,1024) counts | [1024,2048) offsets | [2048,3072) cursor
//                     | [3072,3072+8192) order   => 45 KB total

__global__ __launch_bounds__(256) void zero_counts(int* counts, int* cursor) {
    int i = blockIdx.x * 256 + threadIdx.x;
    if (i < NTASK) { counts[i] = 0; cursor[i] = 0; }
}

__global__ __launch_bounds__(256) void hist_kernel(const int* __restrict__ task_ids,
                                                   int* __restrict__ counts) {
    int i = blockIdx.x * 256 + threadIdx.x;
    if (i < BATCH) atomicAdd(&counts[task_ids[i]], 1);
}

__global__ __launch_bounds__(1024) void scan1024(const int* __restrict__ counts,
                                                 int* __restrict__ offsets) {
    __shared__ int tmp[NTASK];
    int tid = threadIdx.x;
    int v = counts[tid];
    tmp[tid] = v;
    __syncthreads();
    for (int d = 1; d < NTASK; d <<= 1) {
        int t_ = (tid >= d) ? tmp[tid - d] : 0;
        __syncthreads();
        if (tid >= d) tmp[tid] += t_;
        __syncthreads();
    }
    offsets[tid] = tmp[tid] - v;  // exclusive prefix sum
}

__global__ __launch_bounds__(256) void scatter_kernel(const int* __restrict__ task_ids,
                                                      const int* __restrict__ offsets,
                                                      int* __restrict__ cursor,
                                                      int* __restrict__ order) {
    int i = blockIdx.x * 256 + threadIdx.x;
    if (i < BATCH) {
        int t = task_ids[i];
        int pos = atomicAdd(&cursor[t], 1);
        order[offsets[t] + pos] = i;
    }
}

__device__ __forceinline__ float gelu_exact(float s) {
    return 0.5f * s * (1.f + erff(s * 0.70710678118654752440f));
}

__device__ __forceinline__ float4 gelu4(float4 v) {
    return make_float4(gelu_exact(v.x), gelu_exact(v.y), gelu_exact(v.z), gelu_exact(v.w));
}

__device__ __forceinline__ float4 fma4(float s, float4 w, float4 a) {
    a.x = fmaf(s, w.x, a.x); a.y = fmaf(s, w.y, a.y);
    a.z = fmaf(s, w.z, a.z); a.w = fmaf(s, w.w, a.w);
    return a;
}

__device__ __forceinline__ float4 xor_reduce4(float4 v, int m) {
    v.x += __shfl_xor(v.x, m); v.y += __shfl_xor(v.y, m);
    v.z += __shfl_xor(v.z, m); v.w += __shfl_xor(v.w, m);
    return v;
}

__device__ __forceinline__ float4 shfl4(float4 v, int src) {
    return make_float4(__shfl(v.x, src), __shfl(v.y, src),
                       __shfl(v.z, src), __shfl(v.w, src));
}

// One block per task; each WAVE is fully independent (no barriers, no LDS).
// Wave w handles samples base + c0 + 2w, +2w+1 for c0 = 0,8,16,...
// Lane = (grp = lane>>4, c = lane&15): grp owns a 64-row f-slice (layer 1)
// or 16-row hh-slice (layer 2); c owns output column-quad 4c..4c+3.
__global__ __launch_bounds__(256) void mlp_task(
    const float* __restrict__ x,
    const int*   __restrict__ order,
    const int*   __restrict__ counts,
    const int*   __restrict__ offsets,
    const float* __restrict__ l1_emb,
    const float* __restrict__ l2_emb,
    const float* __restrict__ l3_emb,
    float*       __restrict__ out)
{
    const int t = blockIdx.x;
    const int cnt = counts[t];
    if (cnt == 0) return;
    const int base = offsets[t];
    const int tid  = threadIdx.x;
    const int lane = tid & 63;
    const int w    = tid >> 6;
    const int c    = lane & 15;
    const int grp  = lane >> 4;

    const float4* L1 = (const float4*)(l1_emb + (size_t)t * (NF * NH)); // [256][16]
    const float4* L2 = (const float4*)(l2_emb + (size_t)t * (NH * NH)); // [64][16]
    const float4* L3 = (const float4*)(l3_emb + (size_t)t * NH);        // [16]
    const float4* x4 = (const float4*)x;                                // [B][64]

    for (int c0 = 2 * w; c0 < cnt; c0 += 8) {
        const bool v1 = (c0 + 1) < cnt;
        const int  s0 = order[base + c0];
        const int  s1 = v1 ? order[base + c0 + 1] : s0;

        // x rows in registers: lane holds float4-quad `lane` of each row
        float4 xq0 = x4[(size_t)s0 * 64 + lane];
        float4 xq1 = x4[(size_t)s1 * 64 + lane];

        // ---- layer 1: grp's f-slice = grp*64 .. grp*64+63 ----
        float4 a0 = make_float4(0.f, 0.f, 0.f, 0.f);
        float4 a1 = make_float4(0.f, 0.f, 0.f, 0.f);
        #pragma unroll
        for (int q = 0; q < 16; ++q) {
            const int src = grp * 16 + q;        // lane holding x quad (grp*64+4q)/4
            float4 xu0 = shfl4(xq0, src);
            float4 xu1 = shfl4(xq1, src);
            #pragma unroll
            for (int jj = 0; jj < 4; ++jj) {
                const int f = grp * 64 + q * 4 + jj;
                float4 wv4 = L1[f * 16 + c];
                float xv0 = (jj == 0) ? xu0.x : (jj == 1) ? xu0.y : (jj == 2) ? xu0.z : xu0.w;
                float xv1 = (jj == 0) ? xu1.x : (jj == 1) ? xu1.y : (jj == 2) ? xu1.z : xu1.w;
                a0 = fma4(xv0, wv4, a0);
                a1 = fma4(xv1, wv4, a1);
            }
        }
        a0 = xor_reduce4(xor_reduce4(a0, 16), 32);
        a1 = xor_reduce4(xor_reduce4(a1, 16), 32);
        float4 h1q0 = gelu4(a0);   // every lane: h1 columns 4c..4c+3
        float4 h1q1 = gelu4(a1);

        // ---- layer 2: grp's hh-slice = grp*16 .. grp*16+15 ----
        a0 = make_float4(0.f, 0.f, 0.f, 0.f);
        a1 = make_float4(0.f, 0.f, 0.f, 0.f);
        #pragma unroll
        for (int q = 0; q < 4; ++q) {
            const int src = grp * 4 + q;         // lane (row 0) holding h1 quad
            float4 hu0 = shfl4(h1q0, src);
            float4 hu1 = shfl4(h1q1, src);
            #pragma unroll
            for (int jj = 0; jj < 4; ++jj) {
                const int hh = grp * 16 + q * 4 + jj;
                float4 wv4 = L2[hh * 16 + c];
                float hv0 = (jj == 0) ? hu0.x : (jj == 1) ? hu0.y : (jj == 2) ? hu0.z : hu0.w;
                float hv1 = (jj == 0) ? hu1.x : (jj == 1) ? hu1.y : (jj == 2) ? hu1.z : hu1.w;
                a0 = fma4(hv0, wv4, a0);
                a1 = fma4(hv1, wv4, a1);
            }
        }
        a0 = xor_reduce4(xor_reduce4(a0, 16), 32);
        a1 = xor_reduce4(xor_reduce4(a1, 16), 32);
        float4 h2q0 = gelu4(a0);
        float4 h2q1 = gelu4(a1);

        // ---- layer 3: per-lane quad dot, reduce over the 16 c's ----
        float4 l3v = L3[c];
        float d0 = h2q0.x * l3v.x + h2q0.y * l3v.y + h2q0.z * l3v.z + h2q0.w * l3v.w;
        float d1 = h2q1.x * l3v.x + h2q1.y * l3v.y + h2q1.z * l3v.z + h2q1.w * l3v.w;
        #pragma unroll
        for (int m = 1; m < 16; m <<= 1) {
            d0 += __shfl_xor(d0, m);
            d1 += __shfl_xor(d1, m);
        }
        if (lane == 0) {
            out[s0] = 1.f / (1.f + expf(-d0));
            if (v1) out[s1] = 1.f / (1.f + expf(-d1));
        }
    }
}

extern "C" void kernel_launch(void* const* d_in, const int* in_sizes, int n_in,
                              void* d_out, int out_size, void* d_ws, size_t ws_size,
                              hipStream_t stream) {
    const float* x        = (const float*)d_in[0];
    const int*   task_ids = (const int*)  d_in[1];
    const float* l1_emb   = (const float*)d_in[2];
    const float* l2_emb   = (const float*)d_in[3];
    const float* l3_emb   = (const float*)d_in[4];
    float*       out      = (float*)d_out;

    int* ws      = (int*)d_ws;
    int* counts  = ws;
    int* offsets = ws + 1024;
    int* cursor  = ws + 2048;
    int* order   = ws + 3072;

    zero_counts   <<<4, 256, 0, stream>>>(counts, cursor);
    hist_kernel   <<<BATCH / 256, 256, 0, stream>>>(task_ids, counts);
    scan1024      <<<1, 1024, 0, stream>>>(counts, offsets);
    scatter_kernel<<<BATCH / 256, 256, 0, stream>>>(task_ids, offsets, cursor, order);
    mlp_task      <<<NTASK, 256, 0, stream>>>(x, order, counts, offsets,
                                              l1_emb, l2_emb, l3_emb, out);
}

// Round 5
// 38.933 us; speedup vs baseline: 1.7562x; 1.7562x over previous
//
#include <hip/hip_runtime.h>
#include <math.h>

#define BATCH 8192
#define NTASK 1024
#define NF 256
#define NH 64
#define NBLK (BATCH / 2)   // 4096 pair-blocks

// d_ws layout (ints): [0,1024) counts | [1024,2048) offsets | [2048,3072) cursor
//                     | [3072,3072+8192) order packed as (task<<13)|sample  => 45 KB

__global__ __launch_bounds__(256) void zero_counts(int* counts, int* cursor) {
    int i = blockIdx.x * 256 + threadIdx.x;
    if (i < NTASK) { counts[i] = 0; cursor[i] = 0; }
}

__global__ __launch_bounds__(256) void hist_kernel(const int* __restrict__ task_ids,
                                                   int* __restrict__ counts) {
    int i = blockIdx.x * 256 + threadIdx.x;
    if (i < BATCH) atomicAdd(&counts[task_ids[i]], 1);
}

__global__ __launch_bounds__(1024) void scan1024(const int* __restrict__ counts,
                                                 int* __restrict__ offsets) {
    __shared__ int tmp[NTASK];
    int tid = threadIdx.x;
    int v = counts[tid];
    tmp[tid] = v;
    __syncthreads();
    for (int d = 1; d < NTASK; d <<= 1) {
        int t_ = (tid >= d) ? tmp[tid - d] : 0;
        __syncthreads();
        if (tid >= d) tmp[tid] += t_;
        __syncthreads();
    }
    offsets[tid] = tmp[tid] - v;  // exclusive prefix sum
}

__global__ __launch_bounds__(256) void scatter_kernel(const int* __restrict__ task_ids,
                                                      const int* __restrict__ offsets,
                                                      int* __restrict__ cursor,
                                                      int* __restrict__ order) {
    int i = blockIdx.x * 256 + threadIdx.x;
    if (i < BATCH) {
        int t = task_ids[i];
        int pos = atomicAdd(&cursor[t], 1);
        order[offsets[t] + pos] = (t << 13) | i;   // pack task + sample index
    }
}

__device__ __forceinline__ float gelu_exact(float s) {
    return 0.5f * s * (1.f + erff(s * 0.70710678118654752440f));
}

__device__ __forceinline__ float4 gelu4(float4 v) {
    return make_float4(gelu_exact(v.x), gelu_exact(v.y), gelu_exact(v.z), gelu_exact(v.w));
}

__device__ __forceinline__ float4 fma4(float s, float4 w, float4 a) {
    a.x = fmaf(s, w.x, a.x); a.y = fmaf(s, w.y, a.y);
    a.z = fmaf(s, w.z, a.z); a.w = fmaf(s, w.w, a.w);
    return a;
}

__device__ __forceinline__ float4 xor_reduce4(float4 v, int m) {
    v.x += __shfl_xor(v.x, m); v.y += __shfl_xor(v.y, m);
    v.z += __shfl_xor(v.z, m); v.w += __shfl_xor(v.w, m);
    return v;
}

// One block per sorted sample-PAIR. 4 waves; wave w owns f-slice [64w,64w+64)
// for layer 1; layers 2/3 computed redundantly per wave (16KB panel is
// L1-cache resident). Lane = (grp = lane>>4 row-slice, c = lane&15 col-quad).
__global__ __launch_bounds__(256) void mlp_pair(
    const float* __restrict__ x,
    const int*   __restrict__ order,
    const float* __restrict__ l1_emb,
    const float* __restrict__ l2_emb,
    const float* __restrict__ l3_emb,
    float*       __restrict__ out)
{
    // XCD-chunked swizzle: physical P -> logical b so that consecutive sorted
    // pairs (same task) land on the SAME XCD's L2. 4096 % 8 == 0 -> bijective.
    const int P = blockIdx.x;
    const int b = (P & 7) * (NBLK / 8) + (P >> 3);

    const int tid  = threadIdx.x;
    const int lane = tid & 63;
    const int w    = tid >> 6;
    const int c    = lane & 15;
    const int grp  = lane >> 4;

    __shared__ float  xs[2][NF];        // 2 KB
    __shared__ float4 red[4][2][16];    // 2 KB
    __shared__ float4 h1s[2][16];       // 512 B

    const int pk0 = order[2 * b];       // uniform -> scalar loads
    const int pk1 = order[2 * b + 1];
    const int i0 = pk0 & (BATCH - 1), t0 = pk0 >> 13;
    const int i1 = pk1 & (BATCH - 1), t1 = pk1 >> 13;

    // stage both x rows (128 float4)
    const float4* x4 = (const float4*)x;
    if (tid < 128) {
        int s = tid >> 6, q = tid & 63;
        ((float4*)xs)[s * 64 + q] = x4[(size_t)(s ? i1 : i0) * 64 + q];
    }
    __syncthreads();

    // ---- layer 1 ----
    const float4* W1a = (const float4*)(l1_emb + (size_t)t0 * (NF * NH)); // [256][16]
    const float4* W1b = (const float4*)(l1_emb + (size_t)t1 * (NF * NH));
    float4 a0 = make_float4(0.f, 0.f, 0.f, 0.f);
    float4 a1 = make_float4(0.f, 0.f, 0.f, 0.f);
    const int fbase = w * 64 + grp * 16;
    if (t0 == t1) {
        #pragma unroll
        for (int j = 0; j < 16; ++j) {
            const int f = fbase + j;
            float4 wv = W1a[f * 16 + c];
            a0 = fma4(xs[0][f], wv, a0);
            a1 = fma4(xs[1][f], wv, a1);
        }
    } else {
        #pragma unroll
        for (int j = 0; j < 16; ++j) {
            const int f = fbase + j;
            a0 = fma4(xs[0][f], W1a[f * 16 + c], a0);
            a1 = fma4(xs[1][f], W1b[f * 16 + c], a1);
        }
    }
    a0 = xor_reduce4(xor_reduce4(a0, 16), 32);   // sum over grp within wave
    a1 = xor_reduce4(xor_reduce4(a1, 16), 32);
    if (lane < 16) { red[w][0][lane] = a0; red[w][1][lane] = a1; }
    __syncthreads();
    if (tid < 32) {
        int s = tid >> 4, q = tid & 15;
        float4 A = red[0][s][q], B = red[1][s][q], C = red[2][s][q], D = red[3][s][q];
        h1s[s][q] = gelu4(make_float4(A.x + B.x + C.x + D.x, A.y + B.y + C.y + D.y,
                                      A.z + B.z + C.z + D.z, A.w + B.w + C.w + D.w));
    }
    __syncthreads();

    // ---- layer 2 (each wave computes the whole thing; panel is L1-resident) ----
    const float4* W2a = (const float4*)(l2_emb + (size_t)t0 * (NH * NH)); // [64][16]
    const float4* W2b = (const float4*)(l2_emb + (size_t)t1 * (NH * NH));
    float4 b0 = make_float4(0.f, 0.f, 0.f, 0.f);
    float4 b1 = make_float4(0.f, 0.f, 0.f, 0.f);
    const float4 hv0 = h1s[0][grp];   // rows 4grp..4grp+3 multipliers
    const float4 hv1 = h1s[1][grp];
    if (t0 == t1) {
        #pragma unroll
        for (int jj = 0; jj < 4; ++jj) {
            float4 wv = W2a[(grp * 4 + jj) * 16 + c];
            float h0 = (jj == 0) ? hv0.x : (jj == 1) ? hv0.y : (jj == 2) ? hv0.z : hv0.w;
            float h1v = (jj == 0) ? hv1.x : (jj == 1) ? hv1.y : (jj == 2) ? hv1.z : hv1.w;
            b0 = fma4(h0, wv, b0);
            b1 = fma4(h1v, wv, b1);
        }
    } else {
        #pragma unroll
        for (int jj = 0; jj < 4; ++jj) {
            float4 wva = W2a[(grp * 4 + jj) * 16 + c];
            float4 wvb = W2b[(grp * 4 + jj) * 16 + c];
            float h0 = (jj == 0) ? hv0.x : (jj == 1) ? hv0.y : (jj == 2) ? hv0.z : hv0.w;
            float h1v = (jj == 0) ? hv1.x : (jj == 1) ? hv1.y : (jj == 2) ? hv1.z : hv1.w;
            b0 = fma4(h0, wva, b0);
            b1 = fma4(h1v, wvb, b1);
        }
    }
    b0 = xor_reduce4(xor_reduce4(b0, 16), 32);   // full h2 quad c, every lane
    b1 = xor_reduce4(xor_reduce4(b1, 16), 32);
    float4 g0 = gelu4(b0);
    float4 g1 = gelu4(b1);

    // ---- layer 3 ----
    const float4* L3a = (const float4*)(l3_emb + (size_t)t0 * NH);
    const float4* L3b = (const float4*)(l3_emb + (size_t)t1 * NH);
    float4 w3a = L3a[c];
    float4 w3b = (t0 == t1) ? w3a : L3b[c];
    float d0 = g0.x * w3a.x + g0.y * w3a.y + g0.z * w3a.z + g0.w * w3a.w;
    float d1 = g1.x * w3b.x + g1.y * w3b.y + g1.z * w3b.z + g1.w * w3b.w;
    #pragma unroll
    for (int m = 1; m < 16; m <<= 1) {
        d0 += __shfl_xor(d0, m);
        d1 += __shfl_xor(d1, m);
    }
    if (tid == 0) {
        out[i0] = 1.f / (1.f + expf(-d0));
        out[i1] = 1.f / (1.f + expf(-d1));
    }
}

extern "C" void kernel_launch(void* const* d_in, const int* in_sizes, int n_in,
                              void* d_out, int out_size, void* d_ws, size_t ws_size,
                              hipStream_t stream) {
    const float* x        = (const float*)d_in[0];
    const int*   task_ids = (const int*)  d_in[1];
    const float* l1_emb   = (const float*)d_in[2];
    const float* l2_emb   = (const float*)d_in[3];
    const float* l3_emb   = (const float*)d_in[4];
    float*       out      = (float*)d_out;

    int* ws      = (int*)d_ws;
    int* counts  = ws;
    int* offsets = ws + 1024;
    int* cursor  = ws + 2048;
    int* order   = ws + 3072;

    zero_counts   <<<4, 256, 0, stream>>>(counts, cursor);
    hist_kernel   <<<BATCH / 256, 256, 0, stream>>>(task_ids, counts);
    scan1024      <<<1, 1024, 0, stream>>>(counts, offsets);
    scatter_kernel<<<BATCH / 256, 256, 0, stream>>>(task_ids, offsets, cursor, order);
    mlp_pair      <<<NBLK, 256, 0, stream>>>(x, order, l1_emb, l2_emb, l3_emb, out);
}

// Round 6
// 32.467 us; speedup vs baseline: 2.1060x; 1.1991x over previous
//
#include <hip/hip_runtime.h>
#include <math.h>

#define BATCH 8192
#define NTASK 1024
#define NF 256
#define NH 64
#define MAXBLK 2816   // max sum ceil(cnt_t/4) = 2048 + 768

// d_ws layout (ints): [0,8192) order | [8192, 8192+MAXBLK) desc | [8192+MAXBLK] nblk

// ---------- prep: hist + scan + scatter + desc build, ONE block ----------
__global__ __launch_bounds__(1024) void prep_kernel(const int* __restrict__ task_ids,
                                                    int* __restrict__ order,
                                                    int* __restrict__ desc,
                                                    int* __restrict__ nblk) {
    __shared__ int cnt[NTASK];
    __shared__ int tmp[NTASK];
    __shared__ int off[NTASK];
    const int tid = threadIdx.x;

    cnt[tid] = 0;
    __syncthreads();
    #pragma unroll
    for (int k = 0; k < 8; ++k)
        atomicAdd(&cnt[task_ids[tid + k * 1024]], 1);
    __syncthreads();

    const int c = cnt[tid];
    tmp[tid] = c;
    __syncthreads();
    for (int d = 1; d < NTASK; d <<= 1) {
        int t_ = (tid >= d) ? tmp[tid - d] : 0;
        __syncthreads();
        tmp[tid] += t_;
        __syncthreads();
    }
    off[tid] = tmp[tid] - c;            // exclusive prefix
    cnt[tid] = off[tid];                // reuse cnt as cursor
    __syncthreads();

    #pragma unroll
    for (int k = 0; k < 8; ++k) {
        int i = tid + k * 1024;
        int t = task_ids[i];
        int pos = atomicAdd(&cnt[t], 1);
        order[pos] = i;
    }

    // block descriptors: ceil(c/4) blocks per task, all same-task
    const int nb = (c + 3) >> 2;
    __syncthreads();
    tmp[tid] = nb;
    __syncthreads();
    for (int d = 1; d < NTASK; d <<= 1) {
        int t_ = (tid >= d) ? tmp[tid - d] : 0;
        __syncthreads();
        tmp[tid] += t_;
        __syncthreads();
    }
    int bstart = tmp[tid] - nb;
    for (int k = 0; k < nb; ++k) {
        int start = off[tid] + 4 * k;
        int S = min(4, c - 4 * k);
        desc[bstart + k] = (tid << 15) | (start << 2) | (S - 1);
    }
    if (tid == NTASK - 1) nblk[0] = tmp[tid];
}

// ---------- math helpers ----------
__device__ __forceinline__ float gelu_exact(float s) {
    return 0.5f * s * (1.f + erff(s * 0.70710678118654752440f));
}
__device__ __forceinline__ float4 gelu4(float4 v) {
    return make_float4(gelu_exact(v.x), gelu_exact(v.y), gelu_exact(v.z), gelu_exact(v.w));
}
__device__ __forceinline__ float4 fma4(float s, float4 w, float4 a) {
    a.x = fmaf(s, w.x, a.x); a.y = fmaf(s, w.y, a.y);
    a.z = fmaf(s, w.z, a.z); a.w = fmaf(s, w.w, a.w);
    return a;
}
__device__ __forceinline__ float4 xor_reduce4(float4 v, int m) {
    v.x += __shfl_xor(v.x, m); v.y += __shfl_xor(v.y, m);
    v.z += __shfl_xor(v.z, m); v.w += __shfl_xor(v.w, m);
    return v;
}

// ---------- main: one block per task-uniform quad of samples ----------
// 4 waves. Layer 1: wave w owns f-slice [64w, 64w+64), all 4 samples.
// Layer 2/3: wave w computes sample w alone (16KB panel, cache-resident).
// Lane = (grp = lane>>4 row-slice, cq = lane&15 col-quad).
__global__ __launch_bounds__(256) void mlp_quad(
    const float* __restrict__ x,
    const int*   __restrict__ order,
    const int*   __restrict__ desc,
    const int*   __restrict__ nblk,
    const float* __restrict__ l1_emb,
    const float* __restrict__ l2_emb,
    const float* __restrict__ l3_emb,
    float*       __restrict__ out)
{
    const int nb = nblk[0];
    const int P  = blockIdx.x;
    if (P >= nb) return;
    // bijective XCD-chunked swizzle for runtime nb (m204 variant)
    const int qc = nb >> 3, r = nb & 7;
    const int xcd = P & 7, j = P >> 3;
    const int b = (xcd < r ? xcd * (qc + 1) : r * (qc + 1) + (xcd - r) * qc) + j;

    const int d  = desc[b];
    const int S  = (d & 3) + 1;
    const int st = (d >> 2) & 8191;
    const int t  = d >> 15;

    const int tid  = threadIdx.x;
    const int lane = tid & 63;
    const int w    = tid >> 6;
    const int cq   = lane & 15;
    const int grp  = lane >> 4;

    __shared__ float  xs[4][NF];        // 4 KB
    __shared__ float4 red[4][4][16];    // 4 KB  [wave][sample][quad]
    __shared__ float4 h1s[4][16];       // 1 KB
    __shared__ int    sidx[4];

    if (tid < 4) sidx[tid] = order[st + (tid < S ? tid : 0)];
    __syncthreads();

    // stage 4 x rows: 256 float4, one per thread
    {
        const float4* x4 = (const float4*)x;
        int s = tid >> 6, qq = tid & 63;
        ((float4*)xs)[s * 64 + qq] = x4[(size_t)sidx[s] * 64 + qq];
    }
    __syncthreads();

    // ---- layer 1 ----
    const float4* W1 = (const float4*)(l1_emb + (size_t)t * (NF * NH)); // [256][16]
    float4 a0 = make_float4(0.f,0.f,0.f,0.f), a1 = a0, a2 = a0, a3 = a0;
    const int fbase = w * 64 + grp * 16;
    #pragma unroll
    for (int jj = 0; jj < 16; ++jj) {
        const int f = fbase + jj;
        float4 wv = W1[f * 16 + cq];
        a0 = fma4(xs[0][f], wv, a0);
        a1 = fma4(xs[1][f], wv, a1);
        a2 = fma4(xs[2][f], wv, a2);
        a3 = fma4(xs[3][f], wv, a3);
    }
    a0 = xor_reduce4(xor_reduce4(a0, 16), 32);
    a1 = xor_reduce4(xor_reduce4(a1, 16), 32);
    a2 = xor_reduce4(xor_reduce4(a2, 16), 32);
    a3 = xor_reduce4(xor_reduce4(a3, 16), 32);
    if (lane < 16) {
        red[w][0][lane] = a0; red[w][1][lane] = a1;
        red[w][2][lane] = a2; red[w][3][lane] = a3;
    }
    __syncthreads();
    if (tid < 64) {
        int s = tid >> 4, qq = tid & 15;
        float4 A = red[0][s][qq], B = red[1][s][qq], C = red[2][s][qq], D = red[3][s][qq];
        h1s[s][qq] = gelu4(make_float4(A.x+B.x+C.x+D.x, A.y+B.y+C.y+D.y,
                                       A.z+B.z+C.z+D.z, A.w+B.w+C.w+D.w));
    }
    __syncthreads();

    // ---- layer 2/3: wave w -> sample w ----
    const float4* W2 = (const float4*)(l2_emb + (size_t)t * (NH * NH)); // [64][16]
    const float4  hv = h1s[w][grp];   // h1 rows 4grp..4grp+3 of sample w
    float4 acc = make_float4(0.f,0.f,0.f,0.f);
    {
        float4 wv0 = W2[(grp * 4 + 0) * 16 + cq];
        float4 wv1 = W2[(grp * 4 + 1) * 16 + cq];
        float4 wv2 = W2[(grp * 4 + 2) * 16 + cq];
        float4 wv3 = W2[(grp * 4 + 3) * 16 + cq];
        acc = fma4(hv.x, wv0, acc);
        acc = fma4(hv.y, wv1, acc);
        acc = fma4(hv.z, wv2, acc);
        acc = fma4(hv.w, wv3, acc);
    }
    acc = xor_reduce4(xor_reduce4(acc, 16), 32);   // full h2 col-quad cq
    float4 g = gelu4(acc);

    const float4* L3 = (const float4*)(l3_emb + (size_t)t * NH);
    float4 w3 = L3[cq];
    float dot = g.x * w3.x + g.y * w3.y + g.z * w3.z + g.w * w3.w;
    #pragma unroll
    for (int m = 1; m < 16; m <<= 1) dot += __shfl_xor(dot, m);
    if (lane == 0 && w < S)
        out[sidx[w]] = 1.f / (1.f + expf(-dot));
}

extern "C" void kernel_launch(void* const* d_in, const int* in_sizes, int n_in,
                              void* d_out, int out_size, void* d_ws, size_t ws_size,
                              hipStream_t stream) {
    const float* x        = (const float*)d_in[0];
    const int*   task_ids = (const int*)  d_in[1];
    const float* l1_emb   = (const float*)d_in[2];
    const float* l2_emb   = (const float*)d_in[3];
    const float* l3_emb   = (const float*)d_in[4];
    float*       out      = (float*)d_out;

    int* ws    = (int*)d_ws;
    int* order = ws;                 // [0, 8192)
    int* desc  = ws + BATCH;         // [8192, 8192+MAXBLK)
    int* nblk  = ws + BATCH + MAXBLK;

    prep_kernel<<<1, 1024, 0, stream>>>(task_ids, order, desc, nblk);
    mlp_quad   <<<MAXBLK, 256, 0, stream>>>(x, order, desc, nblk,
                                            l1_emb, l2_emb, l3_emb, out);
}

// Round 7
// 28.702 us; speedup vs baseline: 2.3823x; 1.1312x over previous
//
#include <hip/hip_runtime.h>
#include <math.h>

#define BATCH 8192
#define NTASK 1024
#define NF 256
#define NH 64
#define MAXBLK 2816   // max sum ceil(cnt_t/4) = (8192+3*1024)/4

// d_ws layout (ints): [0,8192) order | [8192, 8192+MAXBLK) desc | [8192+MAXBLK] nblk

// ---------- prep: hist + packed double-scan + scatter + desc, ONE block ----------
__global__ __launch_bounds__(1024) void prep_kernel(const int* __restrict__ task_ids,
                                                    int* __restrict__ order,
                                                    int* __restrict__ desc,
                                                    int* __restrict__ nblk) {
    __shared__ int cnt[NTASK];   // histogram, then scatter cursor
    __shared__ int wsum[16];
    const int tid  = threadIdx.x;
    const int lane = tid & 63;
    const int wv   = tid >> 6;

    cnt[tid] = 0;
    __syncthreads();

    int myids[8];
    #pragma unroll
    for (int k = 0; k < 8; ++k) myids[k] = task_ids[tid + k * 1024];
    #pragma unroll
    for (int k = 0; k < 8; ++k) atomicAdd(&cnt[myids[k]], 1);
    __syncthreads();

    const int c  = cnt[tid];
    const int nb = (c + 3) >> 2;
    const int packed = (c << 12) | nb;    // both prefix sums at once

    // inclusive wave-scan (shfl, no barriers)
    int v = packed;
    #pragma unroll
    for (int d = 1; d < 64; d <<= 1) {
        int u = __shfl_up(v, d);
        if (lane >= d) v += u;
    }
    if (lane == 63) wsum[wv] = v;
    __syncthreads();
    if (wv == 0 && lane < 16) {
        int s = wsum[lane];
        #pragma unroll
        for (int d = 1; d < 16; d <<= 1) {
            int u = __shfl_up(s, d);
            if (lane >= d) s += u;
        }
        wsum[lane] = s;                   // inclusive wave sums
    }
    __syncthreads();

    const int incl = ((wv > 0) ? wsum[wv - 1] : 0) + v;
    const int excl = incl - packed;
    const int offC   = excl >> 12;
    const int bstart = excl & 0xFFF;
    if (tid == NTASK - 1) nblk[0] = incl & 0xFFF;
    cnt[tid] = offC;                      // reuse as cursor
    __syncthreads();

    #pragma unroll
    for (int k = 0; k < 8; ++k) {
        int i = tid + k * 1024;
        int pos = atomicAdd(&cnt[myids[k]], 1);
        order[pos] = i;
    }
    for (int k = 0; k < nb; ++k) {
        int S = min(4, c - 4 * k);
        desc[bstart + k] = (tid << 15) | ((offC + 4 * k) << 2) | (S - 1);
    }
}

// ---------- math helpers ----------
__device__ __forceinline__ float gelu_exact(float s) {
    return 0.5f * s * (1.f + erff(s * 0.70710678118654752440f));
}
__device__ __forceinline__ float4 gelu4(float4 v) {
    return make_float4(gelu_exact(v.x), gelu_exact(v.y), gelu_exact(v.z), gelu_exact(v.w));
}
__device__ __forceinline__ float4 fma4(float s, float4 w, float4 a) {
    a.x = fmaf(s, w.x, a.x); a.y = fmaf(s, w.y, a.y);
    a.z = fmaf(s, w.z, a.z); a.w = fmaf(s, w.w, a.w);
    return a;
}
__device__ __forceinline__ float4 xor_reduce4(float4 v, int m) {
    v.x += __shfl_xor(v.x, m); v.y += __shfl_xor(v.y, m);
    v.z += __shfl_xor(v.z, m); v.w += __shfl_xor(v.w, m);
    return v;
}

// ---------- main: one block per task-uniform quad of samples ----------
// 4 waves. Layer 1: wave w owns f-slice [64w, 64w+64), all 4 samples.
// Layer 2/3: wave w computes sample w alone. 2 barriers total.
// Lane = (grp = lane>>4 row-slice, cq = lane&15 col-quad).
__global__ __launch_bounds__(256) void mlp_quad(
    const float* __restrict__ x,
    const int*   __restrict__ order,
    const int*   __restrict__ desc,
    const int*   __restrict__ nblk,
    const float* __restrict__ l1_emb,
    const float* __restrict__ l2_emb,
    const float* __restrict__ l3_emb,
    float*       __restrict__ out)
{
    const int nb = nblk[0];
    const int P  = blockIdx.x;
    if (P >= nb) return;
    // bijective XCD-chunked swizzle for runtime nb (m204 variant)
    const int qc = nb >> 3, r = nb & 7;
    const int xcd = P & 7, j = P >> 3;
    const int b = (xcd < r ? xcd * (qc + 1) : r * (qc + 1) + (xcd - r) * qc) + j;

    const int d  = desc[b];
    const int S  = (d & 3) + 1;
    const int st = (d >> 2) & 8191;
    const int t  = d >> 15;

    const int tid  = threadIdx.x;
    const int lane = tid & 63;
    const int w    = tid >> 6;
    const int cq   = lane & 15;
    const int grp  = lane >> 4;

    __shared__ float  xs[4][NF];        // 4 KB
    __shared__ float4 red[4][4][16];    // 4 KB  [wave][sample][quad]

    // wave-uniform sample index (scalar load); padded waves alias sample 0
    const int myi = order[st + min(w, S - 1)];

    // stage x: wave w stages its own sample's row (64 float4)
    {
        const float4* x4 = (const float4*)x;
        ((float4*)xs)[w * 64 + lane] = x4[(size_t)myi * 64 + lane];
    }
    __syncthreads();

    // ---- layer 1: wave w covers f-slice [64w, 64w+64) for ALL 4 samples ----
    const float4* W1 = (const float4*)(l1_emb + (size_t)t * (NF * NH)); // [256][16]
    float4 a0 = make_float4(0.f,0.f,0.f,0.f), a1 = a0, a2 = a0, a3 = a0;
    const int fbase = w * 64 + grp * 16;
    #pragma unroll
    for (int jj = 0; jj < 16; ++jj) {
        const int f = fbase + jj;
        float4 wv = W1[f * 16 + cq];
        a0 = fma4(xs[0][f], wv, a0);
        a1 = fma4(xs[1][f], wv, a1);
        a2 = fma4(xs[2][f], wv, a2);
        a3 = fma4(xs[3][f], wv, a3);
    }
    a0 = xor_reduce4(xor_reduce4(a0, 16), 32);
    a1 = xor_reduce4(xor_reduce4(a1, 16), 32);
    a2 = xor_reduce4(xor_reduce4(a2, 16), 32);
    a3 = xor_reduce4(xor_reduce4(a3, 16), 32);
    if (lane < 16) {
        red[w][0][lane] = a0; red[w][1][lane] = a1;
        red[w][2][lane] = a2; red[w][3][lane] = a3;
    }
    __syncthreads();

    // finalize h1 quad `grp` of sample `w` in-register (redundant across cq)
    float4 A = red[0][w][grp], B = red[1][w][grp];
    float4 C = red[2][w][grp], D = red[3][w][grp];
    const float4 hv = gelu4(make_float4(A.x+B.x+C.x+D.x, A.y+B.y+C.y+D.y,
                                        A.z+B.z+C.z+D.z, A.w+B.w+C.w+D.w));

    // ---- layer 2: wave w -> sample w ----
    const float4* W2 = (const float4*)(l2_emb + (size_t)t * (NH * NH)); // [64][16]
    float4 acc = make_float4(0.f,0.f,0.f,0.f);
    acc = fma4(hv.x, W2[(grp * 4 + 0) * 16 + cq], acc);
    acc = fma4(hv.y, W2[(grp * 4 + 1) * 16 + cq], acc);
    acc = fma4(hv.z, W2[(grp * 4 + 2) * 16 + cq], acc);
    acc = fma4(hv.w, W2[(grp * 4 + 3) * 16 + cq], acc);
    acc = xor_reduce4(xor_reduce4(acc, 16), 32);   // full h2 col-quad cq
    float4 g = gelu4(acc);

    // ---- layer 3 ----
    const float4* L3 = (const float4*)(l3_emb + (size_t)t * NH);
    float4 w3 = L3[cq];
    float dot = g.x * w3.x + g.y * w3.y + g.z * w3.z + g.w * w3.w;
    #pragma unroll
    for (int m = 1; m < 16; m <<= 1) dot += __shfl_xor(dot, m);
    if (lane == 0 && w < S)
        out[myi] = 1.f / (1.f + expf(-dot));
}

extern "C" void kernel_launch(void* const* d_in, const int* in_sizes, int n_in,
                              void* d_out, int out_size, void* d_ws, size_t ws_size,
                              hipStream_t stream) {
    const float* x        = (const float*)d_in[0];
    const int*   task_ids = (const int*)  d_in[1];
    const float* l1_emb   = (const float*)d_in[2];
    const float* l2_emb   = (const float*)d_in[3];
    const float* l3_emb   = (const float*)d_in[4];
    float*       out      = (float*)d_out;

    int* ws    = (int*)d_ws;
    int* order = ws;                 // [0, 8192)
    int* desc  = ws + BATCH;         // [8192, 8192+MAXBLK)
    int* nblk  = ws + BATCH + MAXBLK;

    prep_kernel<<<1, 1024, 0, stream>>>(task_ids, order, desc, nblk);
    mlp_quad   <<<MAXBLK, 256, 0, stream>>>(x, order, desc, nblk,
                                            l1_emb, l2_emb, l3_emb, out);
}